// Round 1
// 1111.991 us; speedup vs baseline: 2.0477x; 2.0477x over previous
//
#include <hip/hip_runtime.h>

typedef unsigned short u16;
typedef __bf16 bf16x8 __attribute__((ext_vector_type(8)));
typedef short s16x8 __attribute__((ext_vector_type(8)));
typedef u16 u16x4 __attribute__((ext_vector_type(4)));
typedef float f32x4 __attribute__((ext_vector_type(4)));

__device__ __forceinline__ float b2f(u16 u) {
  union { unsigned u32; float f; } x; x.u32 = ((unsigned)u) << 16; return x.f;
}
__device__ __forceinline__ u16 f2b(float f) {
  union { float f; unsigned u; } x; x.f = f;
  unsigned r = x.u + 0x7fffu + ((x.u >> 16) & 1u);
  return (u16)(r >> 16);
}

// Load 8 contiguous elements as bf16 bits; F32=1 converts from float (RNE).
template <int F32>
__device__ __forceinline__ s16x8 load8(const void* __restrict__ p, size_t idx) {
  if (F32) {
    const float* f = (const float*)p + idx;
    f32x4 a = *(const f32x4*)f;
    f32x4 b = *(const f32x4*)(f + 4);
    s16x8 r;
    r[0] = (short)f2b(a[0]); r[1] = (short)f2b(a[1]);
    r[2] = (short)f2b(a[2]); r[3] = (short)f2b(a[3]);
    r[4] = (short)f2b(b[0]); r[5] = (short)f2b(b[1]);
    r[6] = (short)f2b(b[2]); r[7] = (short)f2b(b[3]);
    return r;
  } else {
    return *(const s16x8*)((const u16*)p + idx);
  }
}

// ---------------------------------------------------------------------------
// MFMA bf16 GEMM: C[M,N] = act(A[M,K] * Bt[N,K]^T + bias[N]), f32 acc, bf16 out
// A/Bt are f32 (converted on stage) or bf16 per template. 128x128 tile, BK=32,
// 4 waves as 2x2 of 64x64. M%128==0, N%128==0, K%32==0. grid = (N/128, M/128)
// TRANSC=1: write C transposed per 1024-row panel: C[(row>>10)*N + col][row&1023]
// (used to produce V^T layout vt[b*768+col][s] for the attention PV MFMA).
// ---------------------------------------------------------------------------
template <int RELU, int AF32, int BF32, int TRANSC = 0>
__global__ __launch_bounds__(256) void gemm_bt_kernel(
    const void* __restrict__ A, const void* __restrict__ Bt,
    const float* __restrict__ bias, u16* __restrict__ C,
    int M, int N, int K) {
  __shared__ u16 As[128][32];
  __shared__ u16 Bs[128][32];
  const int tid = threadIdx.x;
  const int lane = tid & 63;
  const int wave = tid >> 6;
  const int wm = wave >> 1, wn = wave & 1;
  const int lr = tid >> 2;             // 0..63 (staging row, x2 halves)
  const int lk = (tid & 3) << 3;       // 0,8,16,24
  const int tn = blockIdx.x, tm = blockIdx.y;
  const size_t abase = (size_t)tm * 128 * K;
  const size_t bbase = (size_t)tn * 128 * K;
  const int fr = lane & 15;            // frag row/col
  const int fk = (lane >> 4) << 3;     // frag k offset
  f32x4 acc[4][4] = {};

  for (int k0 = 0; k0 < K; k0 += 32) {
    *(s16x8*)&As[lr][lk]      = load8<AF32>(A, abase + (size_t)lr * K + k0 + lk);
    *(s16x8*)&As[lr + 64][lk] = load8<AF32>(A, abase + (size_t)(lr + 64) * K + k0 + lk);
    *(s16x8*)&Bs[lr][lk]      = load8<BF32>(Bt, bbase + (size_t)lr * K + k0 + lk);
    *(s16x8*)&Bs[lr + 64][lk] = load8<BF32>(Bt, bbase + (size_t)(lr + 64) * K + k0 + lk);
    __syncthreads();
    bf16x8 af[4], bfv[4];
#pragma unroll
    for (int i = 0; i < 4; ++i)
      af[i] = __builtin_bit_cast(bf16x8, *(const s16x8*)&As[wm * 64 + i * 16 + fr][fk]);
#pragma unroll
    for (int j = 0; j < 4; ++j)
      bfv[j] = __builtin_bit_cast(bf16x8, *(const s16x8*)&Bs[wn * 64 + j * 16 + fr][fk]);
#pragma unroll
    for (int i = 0; i < 4; ++i)
#pragma unroll
      for (int j = 0; j < 4; ++j)
        acc[i][j] = __builtin_amdgcn_mfma_f32_16x16x32_bf16(af[i], bfv[j], acc[i][j], 0, 0, 0);
    __syncthreads();
  }

  // C/D layout: col = lane&15, row = (lane>>4)*4 + reg
  const int row0 = tm * 128 + wm * 64 + ((lane >> 4) << 2);
  const int col0 = tn * 128 + wn * 64 + fr;
  if (TRANSC) {
#pragma unroll
    for (int j = 0; j < 4; ++j) {
      const int col = col0 + j * 16;
      const float bv = bias[col];
#pragma unroll
      for (int i = 0; i < 4; ++i) {
        const int row = row0 + i * 16;   // rows row..row+3 contiguous, same panel
        u16x4 pk;
#pragma unroll
        for (int r = 0; r < 4; ++r) {
          float v = acc[i][j][r] + bv;
          if (RELU) v = fmaxf(v, 0.f);
          pk[r] = f2b(v);
        }
        size_t idx = ((size_t)(row >> 10) * N + col) * 1024 + (row & 1023);
        *(u16x4*)&C[idx] = pk;
      }
    }
  } else {
#pragma unroll
    for (int j = 0; j < 4; ++j) {
      const int col = col0 + j * 16;
      const float bv = bias[col];
#pragma unroll
      for (int i = 0; i < 4; ++i) {
#pragma unroll
        for (int r = 0; r < 4; ++r) {
          float v = acc[i][j][r] + bv;
          if (RELU) v = fmaxf(v, 0.f);
          C[(size_t)(row0 + i * 16 + r) * N + col] = f2b(v);
        }
      }
    }
  }
}

// ---------------------------------------------------------------------------
__device__ __forceinline__ void block_stats(float s, float s2, float* red, int tid,
                                            float& S, float& S2) {
#pragma unroll
  for (int o = 32; o > 0; o >>= 1) { s += __shfl_xor(s, o); s2 += __shfl_xor(s2, o); }
  if ((tid & 63) == 0) { red[tid >> 6] = s; red[4 + (tid >> 6)] = s2; }
  __syncthreads();
  S = red[0] + red[1] + red[2] + red[3];
  S2 = red[4] + red[5] + red[6] + red[7];
}

// t = LN(2*y) with ln1 params; batch-invariant (100 x 768), f32 in/out
__global__ __launch_bounds__(256) void t_kernel(const float* __restrict__ y,
                                                const float* __restrict__ g,
                                                const float* __restrict__ bb,
                                                float* __restrict__ t) {
  const int l = blockIdx.x, tid = threadIdx.x;
  __shared__ float red[8];
  float xv[3], s = 0.f, s2 = 0.f;
#pragma unroll
  for (int i = 0; i < 3; ++i) {
    int e = tid + i * 256;
    float v = 2.f * y[(size_t)l * 768 + e];
    xv[i] = v; s += v; s2 += v * v;
  }
  float S, S2;
  block_stats(s, s2, red, tid, S, S2);
  float mean = S * (1.f / 768.f);
  float var = S2 * (1.f / 768.f) - mean * mean;
  float inv = rsqrtf(var + 1e-5f);
#pragma unroll
  for (int i = 0; i < 3; ++i) {
    int e = tid + i * 256;
    t[(size_t)l * 768 + e] = (xv[i] - mean) * inv * g[e] + bb[e];
  }
}

// q = t @ Wq^T + bq  (100 x 768, K=768), all f32. block per l.
__global__ __launch_bounds__(256) void q_kernel(const float* __restrict__ t,
                                                const float* __restrict__ Wq,
                                                const float* __restrict__ bq,
                                                float* __restrict__ q) {
  const int l = blockIdx.x, tid = threadIdx.x;
  __shared__ __align__(16) float ts[768];
  for (int i = tid; i < 768; i += 256) ts[i] = t[(size_t)l * 768 + i];
  __syncthreads();
  for (int e = tid; e < 768; e += 256) {
    const float* wr = Wq + (size_t)e * 768;
    float acc = bq[e];
    for (int j = 0; j < 768; j += 4) {
      f32x4 wv = *(const f32x4*)&wr[j];
      f32x4 tv = *(const f32x4*)&ts[j];
      acc += wv[0] * tv[0] + wv[1] * tv[1] + wv[2] * tv[2] + wv[3] * tv[3];
    }
    q[(size_t)l * 768 + e] = acc;
  }
}

// c2[l][j] = sum_d y[l,d] * pool[l, 768+d, j] + dup_bias[l*10+j]   (100 x 10)
__global__ __launch_bounds__(256) void c2_kernel(const float* __restrict__ y,
                                                 const float* __restrict__ pool,
                                                 const float* __restrict__ dbias,
                                                 float* __restrict__ c2) {
  const int l = blockIdx.x, tid = threadIdx.x, lane = tid & 63, w = tid >> 6;
  for (int j = w; j < 10; j += 4) {
    float acc = 0.f;
    for (int d = lane; d < 768; d += 64)
      acc += y[(size_t)l * 768 + d] * pool[((size_t)l * 1536 + 768 + d) * 10 + j];
#pragma unroll
    for (int o = 32; o > 0; o >>= 1) acc += __shfl_xor(acc, o);
    if (lane == 0) c2[l * 10 + j] = acc + dbias[l * 10 + j];
  }
}

// ---------------------------------------------------------------------------
// MFMA fused cross-attention. Block = (b, l-tile of 13). 512 threads, 8 waves.
// Per head h: stage q tile bf16 -> QK^T (mfma, waves split S 8x128) -> scores
// f32 in LDS -> softmax (unnormalized exp + rinv, flash-style) -> a_score
// accumulated in REGISTERS across heads (26 VGPR/thread, one coalesced write
// at the end) -> PV (mfma, waves split K=S, A=exp(sc) cvt bf16, B=vt rows)
// -> cross-wave partial reduce in LDS (reusing sc) -> ao write scaled by rinv.
// grid = (32, 8) = 256 blocks = 1/CU.
// ---------------------------------------------------------------------------
__global__ __launch_bounds__(512) void attn_kernel(
    const float* __restrict__ q,      // 100 x 768 f32
    const u16* __restrict__ kmat,     // (32*1024) x 768 bf16
    const u16* __restrict__ vt,       // (32*768) x 1024 bf16: vt[b*768+h*96+d][s]
    u16* __restrict__ ao,             // 3200 x 768 bf16
    float* __restrict__ ascore) {     // 3200 x 1024 f32 (d_out)
  const int b = blockIdx.x;
  const int l0 = blockIdx.y * 13;
  __shared__ float sc[13][1028];                 // 53456 B (stride 1028: 2-way free)
  __shared__ __align__(16) u16 qs[16][96];       // 3072 B
  __shared__ float rinv[16];
  const int tid = threadIdx.x;
  const int lane = tid & 63;
  const int w = tid >> 6;            // 0..7
  const int fr = lane & 15;
  const int hi = lane >> 4;          // 0..3
  const int fk = hi << 3;            // 0,8,16,24
  const int sfr = (fr < 13) ? fr : 12;  // clamped PV A-row (rows 13..15 unused)
  float areg[26];
#pragma unroll
  for (int j = 0; j < 26; ++j) areg[j] = 0.f;

  for (int h = 0; h < 8; ++h) {
    // ---- stage q tile (bf16), rows >=13 or l>=100 zeroed ----
    for (int i = tid; i < 192; i += 512) {   // 16 rows x 12 chunks of 8
      int r = i / 12, c8 = (i % 12) * 8;
      int l = l0 + r;
      s16x8 v = {};
      if (r < 13 && l < 100) v = load8<1>(q, (size_t)l * 768 + h * 96 + c8);
      *(s16x8*)&qs[r][c8] = v;
    }
    __syncthreads();
    // ---- QK^T: wave w owns s in [w*128, w*128+128) ----
    bf16x8 af[3];
#pragma unroll
    for (int kk = 0; kk < 3; ++kk)
      af[kk] = __builtin_bit_cast(bf16x8, *(const s16x8*)&qs[fr][kk * 32 + fk]);
    const u16* kbase = kmat + (size_t)(b * 1024 + w * 128 + fr) * 768 + h * 96 + fk;
#pragma unroll 2
    for (int nt = 0; nt < 8; ++nt) {
      f32x4 acc = {};
      const u16* kp = kbase + (size_t)nt * 16 * 768;
#pragma unroll
      for (int kk = 0; kk < 3; ++kk) {
        bf16x8 bf = __builtin_bit_cast(bf16x8, *(const s16x8*)(kp + kk * 32));
        acc = __builtin_amdgcn_mfma_f32_16x16x32_bf16(af[kk], bf, acc, 0, 0, 0);
      }
      const int s = w * 128 + nt * 16 + fr;
#pragma unroll
      for (int r = 0; r < 4; ++r) {
        int lr = hi * 4 + r;
        if (lr < 13) sc[lr][s] = acc[r] * 0.10206207261596575f;  // 1/sqrt(96)
      }
    }
    __syncthreads();
    // ---- softmax: wave w rows {w, w+8}; store UNNORMALIZED exp + rinv ----
    for (int r = w; r < 13; r += 8) {
      float m = -1e30f;
      for (int i = lane; i < 1024; i += 64) m = fmaxf(m, sc[r][i]);
#pragma unroll
      for (int o = 32; o > 0; o >>= 1) m = fmaxf(m, __shfl_xor(m, o));
      float sum = 0.f;
      for (int i = lane; i < 1024; i += 64) {
        float e = __expf(sc[r][i] - m);
        sc[r][i] = e; sum += e;
      }
#pragma unroll
      for (int o = 32; o > 0; o >>= 1) sum += __shfl_xor(sum, o);
      if (lane == 0) rinv[r] = 1.f / sum;
    }
    __syncthreads();
    // ---- a_score: accumulate normalized probs in registers ----
#pragma unroll
    for (int j = 0; j < 26; ++j) {
      int i = tid + j * 512;
      int r = i >> 10;
      areg[j] += sc[r][i & 1023] * rinv[r];
    }
    // ---- PV: wave w owns k (=s) in [w*128, w*128+128), 4 k-steps ----
    f32x4 pacc[6];
#pragma unroll
    for (int nt = 0; nt < 6; ++nt) pacc[nt] = (f32x4){0.f, 0.f, 0.f, 0.f};
    const u16* vbase = vt + (size_t)(b * 768 + h * 96 + fr) * 1024 + w * 128 + fk;
#pragma unroll 2
    for (int ks = 0; ks < 4; ++ks) {
      const float* sp = &sc[sfr][w * 128 + ks * 32 + fk];
      bf16x8 paf;
#pragma unroll
      for (int j2 = 0; j2 < 8; ++j2) paf[j2] = (__bf16)sp[j2];
#pragma unroll
      for (int nt = 0; nt < 6; ++nt) {
        bf16x8 vf = __builtin_bit_cast(bf16x8,
            *(const s16x8*)(vbase + (size_t)nt * 16 * 1024 + ks * 32));
        pacc[nt] = __builtin_amdgcn_mfma_f32_16x16x32_bf16(paf, vf, pacc[nt], 0, 0, 0);
      }
    }
    __syncthreads();   // all sc reads done; reuse sc as partial buffer
    float* red = &sc[0][0];
#pragma unroll
    for (int nt = 0; nt < 6; ++nt) {
#pragma unroll
      for (int r = 0; r < 4; ++r) {
        int lr = hi * 4 + r;
        if (lr < 13) red[(w * 13 + lr) * 96 + nt * 16 + fr] = pacc[nt][r];
      }
    }
    __syncthreads();
    // ---- cross-wave reduce + ao write (apply rinv here: flash-style) ----
    for (int i = tid; i < 1248; i += 512) {
      int lr = i / 96, d = i % 96;
      float s = 0.f;
#pragma unroll
      for (int w8 = 0; w8 < 8; ++w8) s += red[(w8 * 13 + lr) * 96 + d];
      int l = l0 + lr;
      if (l < 100) ao[(size_t)(b * 100 + l) * 768 + h * 96 + d] = f2b(s * rinv[lr]);
    }
    __syncthreads();
  }
  // ---- write a_score mean ----
#pragma unroll
  for (int j = 0; j < 26; ++j) {
    int i = tid + j * 512;
    int r = i >> 10;
    int l = l0 + r;
    if (l < 100) ascore[(size_t)(b * 100 + l) * 1024 + (i & 1023)] = areg[j] * 0.125f;
  }
}

// ---------------------------------------------------------------------------
// out = LN(base + add) ; base f32 (per-l if flag, else per-row), add bf16.
// g/b f32. Writes f32 (optional) and bf16 (optional). block per row (3200).
// ---------------------------------------------------------------------------
__global__ __launch_bounds__(256) void ln_kernel(
    const float* __restrict__ base, const u16* __restrict__ add,
    const float* __restrict__ g, const float* __restrict__ bb,
    float* __restrict__ outf, u16* __restrict__ outb, int base_per_l) {
  const int row = blockIdx.x, tid = threadIdx.x;
  __shared__ float red[8];
  const size_t boff = (size_t)(base_per_l ? (row % 100) : row) * 768;
  const size_t aoff = (size_t)row * 768;
  float xv[3], s = 0.f, s2 = 0.f;
#pragma unroll
  for (int i = 0; i < 3; ++i) {
    int e = tid + i * 256;
    float v = base[boff + e] + b2f(add[aoff + e]);
    xv[i] = v; s += v; s2 += v * v;
  }
  float S, S2;
  block_stats(s, s2, red, tid, S, S2);
  float mean = S * (1.f / 768.f);
  float var = S2 * (1.f / 768.f) - mean * mean;
  float inv = rsqrtf(var + 1e-5f);
#pragma unroll
  for (int i = 0; i < 3; ++i) {
    int e = tid + i * 256;
    float o = (xv[i] - mean) * inv * g[e] + bb[e];
    if (outf) outf[aoff + e] = o;
    if (outb) outb[aoff + e] = f2b(o);
  }
}

// ---------------------------------------------------------------------------
// logits[b, l*10+j] = sum_{d<768} h[b,l,d] * pool[l,d,j] + c2[l,j]. block per l.
// Writes f32 directly into d_out.
// ---------------------------------------------------------------------------
__global__ __launch_bounds__(256) void groupfc_kernel(
    const u16* __restrict__ h, const float* __restrict__ pool,
    const float* __restrict__ c2, float* __restrict__ logits) {
  const int l = blockIdx.x, tid = threadIdx.x;
  __shared__ float ps[768][10];
  for (int i = tid; i < 7680; i += 256) ps[i / 10][i % 10] = pool[(size_t)l * 15360 + i];
  __syncthreads();
  for (int idx = tid; idx < 320; idx += 256) {
    int bb = idx / 10, j = idx % 10;
    const u16* hr = h + (size_t)(bb * 100 + l) * 768;
    float acc = c2[l * 10 + j];
    for (int d0 = 0; d0 < 768; d0 += 8) {
      s16x8 hv = *(const s16x8*)&hr[d0];
#pragma unroll
      for (int e = 0; e < 8; ++e) acc += b2f((u16)hv[e]) * ps[d0 + e][j];
    }
    logits[bb * 1000 + l * 10 + j] = acc;
  }
}

// ---------------------------------------------------------------------------
extern "C" void kernel_launch(void* const* d_in, const int* in_sizes, int n_in,
                              void* d_out, int out_size, void* d_ws, size_t ws_size,
                              hipStream_t stream) {
  (void)in_sizes; (void)n_in; (void)out_size; (void)ws_size;
  const float* x      = (const float*)d_in[0];
  const float* y      = (const float*)d_in[1];
  const float* embedW = (const float*)d_in[2];
  const float* embedb = (const float*)d_in[3];
  const float* Wq     = (const float*)d_in[4];
  const float* Wk     = (const float*)d_in[5];
  const float* Wv     = (const float*)d_in[6];
  const float* bq     = (const float*)d_in[7];
  const float* bk     = (const float*)d_in[8];
  const float* bv     = (const float*)d_in[9];
  const float* Wo     = (const float*)d_in[10];
  const float* bo     = (const float*)d_in[11];
  const float* ln1g   = (const float*)d_in[12];
  const float* ln1b   = (const float*)d_in[13];
  const float* ln2g   = (const float*)d_in[14];
  const float* ln2b   = (const float*)d_in[15];
  const float* ln3g   = (const float*)d_in[16];
  const float* ln3b   = (const float*)d_in[17];
  const float* W1     = (const float*)d_in[18];
  const float* b1     = (const float*)d_in[19];
  const float* W2     = (const float*)d_in[20];
  const float* b2     = (const float*)d_in[21];
  const float* pool   = (const float*)d_in[22];
  const float* dbias  = (const float*)d_in[23];

  // Workspace layout (peak ~151.6 MB): kws | vt | R(mem, then post-attn) | small
  char* w = (char*)d_ws;
  u16* kws = (u16*)(w);                         // 50,331,648 B
  u16* vt  = (u16*)(w + 50331648);              // 50,331,648 B (V^T panels)
  char* R  = w + 100663296;                     // 50,331,648 B region
  u16*   mem = (u16*)R;                         // dead after V-projection
  u16*   ao  = (u16*)(R + 0);
  u16*   u1  = (u16*)(R + 4915200);
  u16*   t2b = (u16*)(R + 9830400);
  u16*   f1  = (u16*)(R + 14745600);
  u16*   f2  = (u16*)(R + 19660800);
  u16*   hb  = (u16*)(R + 24576000);
  float* t2f = (float*)(R + 29491200);          // +9,830,400 B ends at 39,321,600
  float* tf  = (float*)(w + 150994944);
  float* qf  = (float*)(w + 150994944 + 307200);
  float* c2  = (float*)(w + 150994944 + 614400);

  float* logits = (float*)d_out;
  float* ascore = (float*)d_out + 32000;

  t_kernel<<<dim3(100), dim3(256), 0, stream>>>(y, ln1g, ln1b, tf);
  q_kernel<<<dim3(100), dim3(256), 0, stream>>>(tf, Wq, bq, qf);
  c2_kernel<<<dim3(100), dim3(256), 0, stream>>>(y, pool, dbias, c2);

  gemm_bt_kernel<1, 1, 1><<<dim3(6, 256), dim3(256), 0, stream>>>(x, embedW, embedb, mem, 32768, 768, 2048);
  gemm_bt_kernel<0, 0, 1><<<dim3(6, 256), dim3(256), 0, stream>>>(mem, Wk, bk, kws, 32768, 768, 768);
  gemm_bt_kernel<0, 0, 1, 1><<<dim3(6, 256), dim3(256), 0, stream>>>(mem, Wv, bv, vt, 32768, 768, 768);

  attn_kernel<<<dim3(32, 8), dim3(512), 0, stream>>>(qf, kws, vt, ao, ascore);

  gemm_bt_kernel<0, 0, 1><<<dim3(6, 25), dim3(256), 0, stream>>>(ao, Wo, bo, u1, 3200, 768, 768);
  ln_kernel<<<dim3(3200), dim3(256), 0, stream>>>(tf, u1, ln2g, ln2b, t2f, t2b, 1);
  gemm_bt_kernel<1, 0, 1><<<dim3(6, 25), dim3(256), 0, stream>>>(t2b, W1, b1, f1, 3200, 768, 768);
  gemm_bt_kernel<0, 0, 1><<<dim3(6, 25), dim3(256), 0, stream>>>(f1, W2, b2, f2, 3200, 768, 768);
  ln_kernel<<<dim3(3200), dim3(256), 0, stream>>>(t2f, f2, ln3g, ln3b, (float*)nullptr, hb, 0);
  groupfc_kernel<<<dim3(100), dim3(256), 0, stream>>>(hb, pool, c2, logits);
}

// Round 2
// 1009.924 us; speedup vs baseline: 2.2547x; 1.1011x over previous
//
#include <hip/hip_runtime.h>

typedef unsigned short u16;
typedef __bf16 bf16x8 __attribute__((ext_vector_type(8)));
typedef short s16x8 __attribute__((ext_vector_type(8)));
typedef u16 u16x4 __attribute__((ext_vector_type(4)));
typedef float f32x4 __attribute__((ext_vector_type(4)));

__device__ __forceinline__ float b2f(u16 u) {
  union { unsigned u32; float f; } x; x.u32 = ((unsigned)u) << 16; return x.f;
}
__device__ __forceinline__ u16 f2b(float f) {
  union { float f; unsigned u; } x; x.f = f;
  unsigned r = x.u + 0x7fffu + ((x.u >> 16) & 1u);
  return (u16)(r >> 16);
}

// Load 8 contiguous elements as bf16 bits; F32=1 converts from float (RNE).
template <int F32>
__device__ __forceinline__ s16x8 load8(const void* __restrict__ p, size_t idx) {
  if (F32) {
    const float* f = (const float*)p + idx;
    f32x4 a = *(const f32x4*)f;
    f32x4 b = *(const f32x4*)(f + 4);
    s16x8 r;
    r[0] = (short)f2b(a[0]); r[1] = (short)f2b(a[1]);
    r[2] = (short)f2b(a[2]); r[3] = (short)f2b(a[3]);
    r[4] = (short)f2b(b[0]); r[5] = (short)f2b(b[1]);
    r[6] = (short)f2b(b[2]); r[7] = (short)f2b(b[3]);
    return r;
  } else {
    return *(const s16x8*)((const u16*)p + idx);
  }
}

// Async global->LDS, 16B per lane. LDS dest = wave-uniform base + lane*16.
__device__ __forceinline__ void gl16(const u16* g, u16* l) {
  __builtin_amdgcn_global_load_lds(
      (const __attribute__((address_space(1))) void*)g,
      (__attribute__((address_space(3))) void*)l, 16, 0, 0);
}

// f32 -> bf16 conversion (weights), n8 = n/8 chunks.
__global__ __launch_bounds__(256) void cvt_kernel(const float* __restrict__ in,
                                                  u16* __restrict__ out, int n8) {
  int i = blockIdx.x * 256 + threadIdx.x;
  if (i < n8) *(s16x8*)&out[(size_t)i * 8] = load8<1>(in, (size_t)i * 8);
}

__global__ __launch_bounds__(256) void cvt3_kernel(
    const float* __restrict__ a, const float* __restrict__ b,
    const float* __restrict__ c, u16* __restrict__ oa, u16* __restrict__ ob,
    u16* __restrict__ oc, int n8) {
  int i = blockIdx.x * 256 + threadIdx.x;
  const float* in = blockIdx.y == 0 ? a : (blockIdx.y == 1 ? b : c);
  u16* out = blockIdx.y == 0 ? oa : (blockIdx.y == 1 ? ob : oc);
  if (i < n8) *(s16x8*)&out[(size_t)i * 8] = load8<1>(in, (size_t)i * 8);
}

// ---------------------------------------------------------------------------
// MFMA bf16 GEMM: C[M,N] = act(A[M,K] * Bt[N,K]^T + bias[N]), f32 acc, bf16 out
// Bt is ALWAYS bf16 (pre-converted weights) and staged via global_load_lds.
// A: AF32=1 -> f32, reg-staged with convert; AF32=0 -> bf16 via global_load_lds.
// 128x128 tile, BK=32, 4 waves as 2x2 of 64x64. 1D grid with bijective
// XCD swizzle (groups the N/128 column-tiles of one A-panel on one XCD).
// TRANSC=1: write C transposed per 1024-row panel (V^T layout for attention).
// ---------------------------------------------------------------------------
template <int RELU, int AF32, int TRANSC>
__global__ __launch_bounds__(256) void gemm_bt_kernel(
    const void* __restrict__ A, const u16* __restrict__ Bt,
    const float* __restrict__ bias, u16* __restrict__ C,
    int M, int N, int K) {
  __shared__ u16 As[128][32];
  __shared__ u16 Bs[128][32];
  const int tid = threadIdx.x;
  const int lane = tid & 63;
  const int wave = tid >> 6;
  const int wm = wave >> 1, wn = wave & 1;
  // bijective XCD swizzle (assumes HW round-robins blockIdx % 8 over XCDs)
  const int nwg = gridDim.x;
  const int orig = blockIdx.x;
  const int q = nwg >> 3, r = nwg & 7;
  const int xcd = orig & 7, loc = orig >> 3;
  const int wgid = (xcd < r ? xcd * (q + 1) : r * (q + 1) + (xcd - r) * q) + loc;
  const int NT = N >> 7;
  const int tn = wgid % NT, tm = wgid / NT;
  const size_t abase = (size_t)tm * 128 * K;
  const size_t bbase = (size_t)tn * 128 * K;
  const int fr = lane & 15;            // frag row/col
  const int fk = (lane >> 4) << 3;     // frag k offset
  // global_load_lds staging coords: lane i covers row (i>>2), k-chunk (i&3)*8
  const int grow = lane >> 2;
  const int gkoff = (lane & 3) << 3;
  const u16* bgp = Bt + bbase + (size_t)(wave * 32 + grow) * K + gkoff;
  u16* lB0 = &Bs[wave * 32][0];
  u16* lB1 = &Bs[wave * 32 + 16][0];
  const u16* agp = nullptr;
  u16 *lA0 = nullptr, *lA1 = nullptr;
  if (!AF32) {
    agp = (const u16*)A + abase + (size_t)(wave * 32 + grow) * K + gkoff;
    lA0 = &As[wave * 32][0];
    lA1 = &As[wave * 32 + 16][0];
  }
  const int lr = tid >> 2;             // AF32 reg-staging: rows 0..63 (+64)
  const int lk = (tid & 3) << 3;
  f32x4 acc[4][4] = {};

  for (int k0 = 0; k0 < K; k0 += 32) {
    if (AF32) {
      *(s16x8*)&As[lr][lk]      = load8<1>(A, abase + (size_t)lr * K + k0 + lk);
      *(s16x8*)&As[lr + 64][lk] = load8<1>(A, abase + (size_t)(lr + 64) * K + k0 + lk);
    } else {
      gl16(agp + k0, lA0);
      gl16(agp + k0 + (size_t)16 * K, lA1);
    }
    gl16(bgp + k0, lB0);
    gl16(bgp + k0 + (size_t)16 * K, lB1);
    __syncthreads();
    bf16x8 af[4], bfv[4];
#pragma unroll
    for (int i = 0; i < 4; ++i)
      af[i] = __builtin_bit_cast(bf16x8, *(const s16x8*)&As[wm * 64 + i * 16 + fr][fk]);
#pragma unroll
    for (int j = 0; j < 4; ++j)
      bfv[j] = __builtin_bit_cast(bf16x8, *(const s16x8*)&Bs[wn * 64 + j * 16 + fr][fk]);
#pragma unroll
    for (int i = 0; i < 4; ++i)
#pragma unroll
      for (int j = 0; j < 4; ++j)
        acc[i][j] = __builtin_amdgcn_mfma_f32_16x16x32_bf16(af[i], bfv[j], acc[i][j], 0, 0, 0);
    __syncthreads();
  }

  // C/D layout: col = lane&15, row = (lane>>4)*4 + reg
  const int row0 = tm * 128 + wm * 64 + ((lane >> 4) << 2);
  const int col0 = tn * 128 + wn * 64 + fr;
  if (TRANSC) {
#pragma unroll
    for (int j = 0; j < 4; ++j) {
      const int col = col0 + j * 16;
      const float bv = bias[col];
#pragma unroll
      for (int i = 0; i < 4; ++i) {
        const int row = row0 + i * 16;   // rows row..row+3 contiguous, same panel
        u16x4 pk;
#pragma unroll
        for (int r2 = 0; r2 < 4; ++r2) {
          float v = acc[i][j][r2] + bv;
          if (RELU) v = fmaxf(v, 0.f);
          pk[r2] = f2b(v);
        }
        size_t idx = ((size_t)(row >> 10) * N + col) * 1024 + (row & 1023);
        *(u16x4*)&C[idx] = pk;
      }
    }
  } else {
#pragma unroll
    for (int j = 0; j < 4; ++j) {
      const int col = col0 + j * 16;
      const float bv = bias[col];
#pragma unroll
      for (int i = 0; i < 4; ++i) {
#pragma unroll
        for (int r2 = 0; r2 < 4; ++r2) {
          float v = acc[i][j][r2] + bv;
          if (RELU) v = fmaxf(v, 0.f);
          C[(size_t)(row0 + i * 16 + r2) * N + col] = f2b(v);
        }
      }
    }
  }
}

// ---------------------------------------------------------------------------
__device__ __forceinline__ void block_stats(float s, float s2, float* red, int tid,
                                            float& S, float& S2) {
#pragma unroll
  for (int o = 32; o > 0; o >>= 1) { s += __shfl_xor(s, o); s2 += __shfl_xor(s2, o); }
  if ((tid & 63) == 0) { red[tid >> 6] = s; red[4 + (tid >> 6)] = s2; }
  __syncthreads();
  S = red[0] + red[1] + red[2] + red[3];
  S2 = red[4] + red[5] + red[6] + red[7];
}

// t = LN(2*y) with ln1 params; batch-invariant (100 x 768), f32 in/out
__global__ __launch_bounds__(256) void t_kernel(const float* __restrict__ y,
                                                const float* __restrict__ g,
                                                const float* __restrict__ bb,
                                                float* __restrict__ t) {
  const int l = blockIdx.x, tid = threadIdx.x;
  __shared__ float red[8];
  float xv[3], s = 0.f, s2 = 0.f;
#pragma unroll
  for (int i = 0; i < 3; ++i) {
    int e = tid + i * 256;
    float v = 2.f * y[(size_t)l * 768 + e];
    xv[i] = v; s += v; s2 += v * v;
  }
  float S, S2;
  block_stats(s, s2, red, tid, S, S2);
  float mean = S * (1.f / 768.f);
  float var = S2 * (1.f / 768.f) - mean * mean;
  float inv = rsqrtf(var + 1e-5f);
#pragma unroll
  for (int i = 0; i < 3; ++i) {
    int e = tid + i * 256;
    t[(size_t)l * 768 + e] = (xv[i] - mean) * inv * g[e] + bb[e];
  }
}

// q = t @ Wq^T + bq  (100 x 768, K=768), all f32. block per l.
__global__ __launch_bounds__(256) void q_kernel(const float* __restrict__ t,
                                                const float* __restrict__ Wq,
                                                const float* __restrict__ bq,
                                                float* __restrict__ q) {
  const int l = blockIdx.x, tid = threadIdx.x;
  __shared__ __align__(16) float ts[768];
  for (int i = tid; i < 768; i += 256) ts[i] = t[(size_t)l * 768 + i];
  __syncthreads();
  for (int e = tid; e < 768; e += 256) {
    const float* wr = Wq + (size_t)e * 768;
    float acc = bq[e];
    for (int j = 0; j < 768; j += 4) {
      f32x4 wv = *(const f32x4*)&wr[j];
      f32x4 tv = *(const f32x4*)&ts[j];
      acc += wv[0] * tv[0] + wv[1] * tv[1] + wv[2] * tv[2] + wv[3] * tv[3];
    }
    q[(size_t)l * 768 + e] = acc;
  }
}

// c2[l][j] = sum_d y[l,d] * pool[l, 768+d, j] + dup_bias[l*10+j]   (100 x 10)
__global__ __launch_bounds__(256) void c2_kernel(const float* __restrict__ y,
                                                 const float* __restrict__ pool,
                                                 const float* __restrict__ dbias,
                                                 float* __restrict__ c2) {
  const int l = blockIdx.x, tid = threadIdx.x, lane = tid & 63, w = tid >> 6;
  for (int j = w; j < 10; j += 4) {
    float acc = 0.f;
    for (int d = lane; d < 768; d += 64)
      acc += y[(size_t)l * 768 + d] * pool[((size_t)l * 1536 + 768 + d) * 10 + j];
#pragma unroll
    for (int o = 32; o > 0; o >>= 1) acc += __shfl_xor(acc, o);
    if (lane == 0) c2[l * 10 + j] = acc + dbias[l * 10 + j];
  }
}

// ---------------------------------------------------------------------------
// MFMA fused cross-attention (see round-1 notes). grid=(32,8), 512 thr, 8 waves.
// ---------------------------------------------------------------------------
__global__ __launch_bounds__(512) void attn_kernel(
    const float* __restrict__ q,      // 100 x 768 f32
    const u16* __restrict__ kmat,     // (32*1024) x 768 bf16
    const u16* __restrict__ vt,       // (32*768) x 1024 bf16: vt[b*768+h*96+d][s]
    u16* __restrict__ ao,             // 3200 x 768 bf16
    float* __restrict__ ascore) {     // 3200 x 1024 f32 (d_out)
  const int b = blockIdx.x;
  const int l0 = blockIdx.y * 13;
  __shared__ float sc[13][1028];                 // 53456 B (stride 1028: 2-way free)
  __shared__ __align__(16) u16 qs[16][96];       // 3072 B
  __shared__ float rinv[16];
  const int tid = threadIdx.x;
  const int lane = tid & 63;
  const int w = tid >> 6;            // 0..7
  const int fr = lane & 15;
  const int hi = lane >> 4;          // 0..3
  const int fk = hi << 3;            // 0,8,16,24
  const int sfr = (fr < 13) ? fr : 12;  // clamped PV A-row (rows 13..15 unused)
  float areg[26];
#pragma unroll
  for (int j = 0; j < 26; ++j) areg[j] = 0.f;

  for (int h = 0; h < 8; ++h) {
    // ---- stage q tile (bf16), rows >=13 or l>=100 zeroed ----
    for (int i = tid; i < 192; i += 512) {   // 16 rows x 12 chunks of 8
      int r = i / 12, c8 = (i % 12) * 8;
      int l = l0 + r;
      s16x8 v = {};
      if (r < 13 && l < 100) v = load8<1>(q, (size_t)l * 768 + h * 96 + c8);
      *(s16x8*)&qs[r][c8] = v;
    }
    __syncthreads();
    // ---- QK^T: wave w owns s in [w*128, w*128+128) ----
    bf16x8 af[3];
#pragma unroll
    for (int kk = 0; kk < 3; ++kk)
      af[kk] = __builtin_bit_cast(bf16x8, *(const s16x8*)&qs[fr][kk * 32 + fk]);
    const u16* kbase = kmat + (size_t)(b * 1024 + w * 128 + fr) * 768 + h * 96 + fk;
#pragma unroll 2
    for (int nt = 0; nt < 8; ++nt) {
      f32x4 acc = {};
      const u16* kp = kbase + (size_t)nt * 16 * 768;
#pragma unroll
      for (int kk = 0; kk < 3; ++kk) {
        bf16x8 bf = __builtin_bit_cast(bf16x8, *(const s16x8*)(kp + kk * 32));
        acc = __builtin_amdgcn_mfma_f32_16x16x32_bf16(af[kk], bf, acc, 0, 0, 0);
      }
      const int s = w * 128 + nt * 16 + fr;
#pragma unroll
      for (int r = 0; r < 4; ++r) {
        int lr2 = hi * 4 + r;
        if (lr2 < 13) sc[lr2][s] = acc[r] * 0.10206207261596575f;  // 1/sqrt(96)
      }
    }
    __syncthreads();
    // ---- softmax: wave w rows {w, w+8}; store UNNORMALIZED exp + rinv ----
    for (int r = w; r < 13; r += 8) {
      float m = -1e30f;
      for (int i = lane; i < 1024; i += 64) m = fmaxf(m, sc[r][i]);
#pragma unroll
      for (int o = 32; o > 0; o >>= 1) m = fmaxf(m, __shfl_xor(m, o));
      float sum = 0.f;
      for (int i = lane; i < 1024; i += 64) {
        float e = __expf(sc[r][i] - m);
        sc[r][i] = e; sum += e;
      }
#pragma unroll
      for (int o = 32; o > 0; o >>= 1) sum += __shfl_xor(sum, o);
      if (lane == 0) rinv[r] = 1.f / sum;
    }
    __syncthreads();
    // ---- a_score: accumulate normalized probs in registers ----
#pragma unroll
    for (int j = 0; j < 26; ++j) {
      int i = tid + j * 512;
      int r = i >> 10;
      areg[j] += sc[r][i & 1023] * rinv[r];
    }
    // ---- PV: wave w owns k (=s) in [w*128, w*128+128), 4 k-steps ----
    f32x4 pacc[6];
#pragma unroll
    for (int nt = 0; nt < 6; ++nt) pacc[nt] = (f32x4){0.f, 0.f, 0.f, 0.f};
    const u16* vbase = vt + (size_t)(b * 768 + h * 96 + fr) * 1024 + w * 128 + fk;
#pragma unroll 2
    for (int ks = 0; ks < 4; ++ks) {
      const float* sp = &sc[sfr][w * 128 + ks * 32 + fk];
      bf16x8 paf;
#pragma unroll
      for (int j2 = 0; j2 < 8; ++j2) paf[j2] = (__bf16)sp[j2];
#pragma unroll
      for (int nt = 0; nt < 6; ++nt) {
        bf16x8 vf = __builtin_bit_cast(bf16x8,
            *(const s16x8*)(vbase + (size_t)nt * 16 * 1024 + ks * 32));
        pacc[nt] = __builtin_amdgcn_mfma_f32_16x16x32_bf16(paf, vf, pacc[nt], 0, 0, 0);
      }
    }
    __syncthreads();   // all sc reads done; reuse sc as partial buffer
    float* red = &sc[0][0];
#pragma unroll
    for (int nt = 0; nt < 6; ++nt) {
#pragma unroll
      for (int r = 0; r < 4; ++r) {
        int lr2 = hi * 4 + r;
        if (lr2 < 13) red[(w * 13 + lr2) * 96 + nt * 16 + fr] = pacc[nt][r];
      }
    }
    __syncthreads();
    // ---- cross-wave reduce + ao write (apply rinv here: flash-style) ----
    for (int i = tid; i < 1248; i += 512) {
      int lr2 = i / 96, d = i % 96;
      float s = 0.f;
#pragma unroll
      for (int w8 = 0; w8 < 8; ++w8) s += red[(w8 * 13 + lr2) * 96 + d];
      int l = l0 + lr2;
      if (l < 100) ao[(size_t)(b * 100 + l) * 768 + h * 96 + d] = f2b(s * rinv[lr2]);
    }
    __syncthreads();
  }
  // ---- write a_score mean ----
#pragma unroll
  for (int j = 0; j < 26; ++j) {
    int i = tid + j * 512;
    int r = i >> 10;
    int l = l0 + r;
    if (l < 100) ascore[(size_t)(b * 100 + l) * 1024 + (i & 1023)] = areg[j] * 0.125f;
  }
}

// ---------------------------------------------------------------------------
// out = LN(base + add) ; base f32 (per-l if flag, else per-row), add bf16.
// ---------------------------------------------------------------------------
__global__ __launch_bounds__(256) void ln_kernel(
    const float* __restrict__ base, const u16* __restrict__ add,
    const float* __restrict__ g, const float* __restrict__ bb,
    float* __restrict__ outf, u16* __restrict__ outb, int base_per_l) {
  const int row = blockIdx.x, tid = threadIdx.x;
  __shared__ float red[8];
  const size_t boff = (size_t)(base_per_l ? (row % 100) : row) * 768;
  const size_t aoff = (size_t)row * 768;
  float xv[3], s = 0.f, s2 = 0.f;
#pragma unroll
  for (int i = 0; i < 3; ++i) {
    int e = tid + i * 256;
    float v = base[boff + e] + b2f(add[aoff + e]);
    xv[i] = v; s += v; s2 += v * v;
  }
  float S, S2;
  block_stats(s, s2, red, tid, S, S2);
  float mean = S * (1.f / 768.f);
  float var = S2 * (1.f / 768.f) - mean * mean;
  float inv = rsqrtf(var + 1e-5f);
#pragma unroll
  for (int i = 0; i < 3; ++i) {
    int e = tid + i * 256;
    float o = (xv[i] - mean) * inv * g[e] + bb[e];
    if (outf) outf[aoff + e] = o;
    if (outb) outb[aoff + e] = f2b(o);
  }
}

// ---------------------------------------------------------------------------
// logits[b, l*10+j] = sum_{d<768} h[b,l,d] * pool[l,d,j] + c2[l,j]. block per l.
// ---------------------------------------------------------------------------
__global__ __launch_bounds__(256) void groupfc_kernel(
    const u16* __restrict__ h, const float* __restrict__ pool,
    const float* __restrict__ c2, float* __restrict__ logits) {
  const int l = blockIdx.x, tid = threadIdx.x;
  __shared__ float ps[768][10];
  for (int i = tid; i < 7680; i += 256) ps[i / 10][i % 10] = pool[(size_t)l * 15360 + i];
  __syncthreads();
  for (int idx = tid; idx < 320; idx += 256) {
    int bb = idx / 10, j = idx % 10;
    const u16* hr = h + (size_t)(bb * 100 + l) * 768;
    float acc = c2[l * 10 + j];
    for (int d0 = 0; d0 < 768; d0 += 8) {
      s16x8 hv = *(const s16x8*)&hr[d0];
#pragma unroll
      for (int e = 0; e < 8; ++e) acc += b2f((u16)hv[e]) * ps[d0 + e][j];
    }
    logits[bb * 1000 + l * 10 + j] = acc;
  }
}

// ---------------------------------------------------------------------------
extern "C" void kernel_launch(void* const* d_in, const int* in_sizes, int n_in,
                              void* d_out, int out_size, void* d_ws, size_t ws_size,
                              hipStream_t stream) {
  (void)in_sizes; (void)n_in; (void)out_size; (void)ws_size;
  const float* x      = (const float*)d_in[0];
  const float* y      = (const float*)d_in[1];
  const float* embedW = (const float*)d_in[2];
  const float* embedb = (const float*)d_in[3];
  const float* Wq     = (const float*)d_in[4];
  const float* Wk     = (const float*)d_in[5];
  const float* Wv     = (const float*)d_in[6];
  const float* bq     = (const float*)d_in[7];
  const float* bk     = (const float*)d_in[8];
  const float* bv     = (const float*)d_in[9];
  const float* Wo     = (const float*)d_in[10];
  const float* bo     = (const float*)d_in[11];
  const float* ln1g   = (const float*)d_in[12];
  const float* ln1b   = (const float*)d_in[13];
  const float* ln2g   = (const float*)d_in[14];
  const float* ln2b   = (const float*)d_in[15];
  const float* ln3g   = (const float*)d_in[16];
  const float* ln3b   = (const float*)d_in[17];
  const float* W1     = (const float*)d_in[18];
  const float* b1     = (const float*)d_in[19];
  const float* W2     = (const float*)d_in[20];
  const float* b2     = (const float*)d_in[21];
  const float* pool   = (const float*)d_in[22];
  const float* dbias  = (const float*)d_in[23];

  // Workspace layout (peak ~153.2 MB): kws | vt | R(mem, then post-attn) | small
  char* w = (char*)d_ws;
  u16* kws = (u16*)(w);                         // 50,331,648 B
  u16* vt  = (u16*)(w + 50331648);              // 50,331,648 B (V^T panels)
  char* R  = w + 100663296;                     // 50,331,648 B region
  u16*   mem = (u16*)R;                         // dead after V-projection
  u16*   ao  = (u16*)(R + 0);
  u16*   u1  = (u16*)(R + 4915200);
  u16*   t2b = (u16*)(R + 9830400);
  u16*   f1  = (u16*)(R + 14745600);
  u16*   f2  = (u16*)(R + 19660800);
  u16*   hb  = (u16*)(R + 24576000);
  float* t2f = (float*)(R + 29491200);          // +9,830,400 B ends at 39,321,600
  float* tf  = (float*)(w + 150994944);
  float* qf  = (float*)(w + 150994944 + 307200);
  float* c2  = (float*)(w + 150994944 + 614400);
  // bf16 weight staging (liveness-overlapped):
  u16* wbE = (u16*)(w + 50331648);              // in vt (dead before V-proj writes)
  u16* wbK = (u16*)(w + 50331648 + 3145728);    // in vt, read by K-proj only
  u16* wbV = (u16*)(w + 150994944 + 1048576);   // own slot (+1.18 MB, peak 153.2 MB)
  u16* wbO = (u16*)(w + 0);                     // in kws (dead after attn)
  u16* wb1 = (u16*)(w + 1179648);
  u16* wb2 = (u16*)(w + 2359296);

  float* logits = (float*)d_out;
  float* ascore = (float*)d_out + 32000;

  cvt_kernel<<<dim3(768), dim3(256), 0, stream>>>(embedW, wbE, 196608);
  cvt_kernel<<<dim3(288), dim3(256), 0, stream>>>(Wk, wbK, 73728);
  cvt_kernel<<<dim3(288), dim3(256), 0, stream>>>(Wv, wbV, 73728);
  t_kernel<<<dim3(100), dim3(256), 0, stream>>>(y, ln1g, ln1b, tf);
  q_kernel<<<dim3(100), dim3(256), 0, stream>>>(tf, Wq, bq, qf);
  c2_kernel<<<dim3(100), dim3(256), 0, stream>>>(y, pool, dbias, c2);

  gemm_bt_kernel<1, 1, 0><<<dim3(1536), dim3(256), 0, stream>>>(x, wbE, embedb, mem, 32768, 768, 2048);
  gemm_bt_kernel<0, 0, 0><<<dim3(1536), dim3(256), 0, stream>>>(mem, wbK, bk, kws, 32768, 768, 768);
  gemm_bt_kernel<0, 0, 1><<<dim3(1536), dim3(256), 0, stream>>>(mem, wbV, bv, vt, 32768, 768, 768);

  attn_kernel<<<dim3(32, 8), dim3(512), 0, stream>>>(qf, kws, vt, ao, ascore);

  cvt3_kernel<<<dim3(288, 3), dim3(256), 0, stream>>>(Wo, W1, W2, wbO, wb1, wb2, 73728);
  gemm_bt_kernel<0, 0, 0><<<dim3(150), dim3(256), 0, stream>>>(ao, wbO, bo, u1, 3200, 768, 768);
  ln_kernel<<<dim3(3200), dim3(256), 0, stream>>>(tf, u1, ln2g, ln2b, t2f, t2b, 1);
  gemm_bt_kernel<1, 0, 0><<<dim3(150), dim3(256), 0, stream>>>(t2b, wb1, b1, f1, 3200, 768, 768);
  gemm_bt_kernel<0, 0, 0><<<dim3(150), dim3(256), 0, stream>>>(f1, wb2, b2, f2, 3200, 768, 768);
  ln_kernel<<<dim3(3200), dim3(256), 0, stream>>>(t2f, f2, ln3g, ln3b, (float*)nullptr, hb, 0);
  groupfc_kernel<<<dim3(100), dim3(256), 0, stream>>>(hb, pool, c2, logits);
}

// Round 3
// 980.103 us; speedup vs baseline: 2.3233x; 1.0304x over previous
//
#include <hip/hip_runtime.h>

typedef unsigned short u16;
typedef __bf16 bf16x8 __attribute__((ext_vector_type(8)));
typedef short s16x8 __attribute__((ext_vector_type(8)));
typedef u16 u16x4 __attribute__((ext_vector_type(4)));
typedef float f32x4 __attribute__((ext_vector_type(4)));

__device__ __forceinline__ float b2f(u16 u) {
  union { unsigned u32; float f; } x; x.u32 = ((unsigned)u) << 16; return x.f;
}
// Native RNE f32->bf16 (compiler emits v_cvt_pk_bf16_f32; bit-identical to
// the manual +0x7fff+lsb rounding for finite values).
__device__ __forceinline__ u16 f2b(float f) {
  return __builtin_bit_cast(u16, (__bf16)f);
}
__device__ __forceinline__ s16x8 cvt8(f32x4 a, f32x4 b) {
  s16x8 r;
#pragma unroll
  for (int i = 0; i < 4; ++i) {
    r[i]     = (short)f2b(a[i]);
    r[i + 4] = (short)f2b(b[i]);
  }
  return r;
}

// Load 8 contiguous elements as bf16 bits; F32=1 converts from float (RNE).
template <int F32>
__device__ __forceinline__ s16x8 load8(const void* __restrict__ p, size_t idx) {
  if (F32) {
    const float* f = (const float*)p + idx;
    return cvt8(*(const f32x4*)f, *(const f32x4*)(f + 4));
  } else {
    return *(const s16x8*)((const u16*)p + idx);
  }
}

// Async global->LDS, 16B per lane. LDS dest = wave-uniform base + lane*16.
__device__ __forceinline__ void gl16(const u16* g, u16* l) {
  __builtin_amdgcn_global_load_lds(
      (const __attribute__((address_space(1))) void*)g,
      (__attribute__((address_space(3))) void*)l, 16, 0, 0);
}

// f32 -> bf16 conversion (weights), n8 = n/8 chunks.
__global__ __launch_bounds__(256) void cvt_kernel(const float* __restrict__ in,
                                                  u16* __restrict__ out, int n8) {
  int i = blockIdx.x * 256 + threadIdx.x;
  if (i < n8) *(s16x8*)&out[(size_t)i * 8] = load8<1>(in, (size_t)i * 8);
}

__global__ __launch_bounds__(256) void cvt3_kernel(
    const float* __restrict__ a, const float* __restrict__ b,
    const float* __restrict__ c, u16* __restrict__ oa, u16* __restrict__ ob,
    u16* __restrict__ oc, int n8) {
  int i = blockIdx.x * 256 + threadIdx.x;
  const float* in = blockIdx.y == 0 ? a : (blockIdx.y == 1 ? b : c);
  u16* out = blockIdx.y == 0 ? oa : (blockIdx.y == 1 ? ob : oc);
  if (i < n8) *(s16x8*)&out[(size_t)i * 8] = load8<1>(in, (size_t)i * 8);
}

// ---------------------------------------------------------------------------
// MFMA bf16 GEMM: C[M,N] = act(A[M,K] * Bt[N,K]^T + bias[N]), f32 acc, bf16 out
// 2-PHASE DOUBLE-BUFFERED k-loop with counted vmcnt (T3/T4): tile t+1's
// staging loads stay in flight across the barrier while tile t's MFMA runs.
// Bt always bf16 via global_load_lds. A: AF32=1 f32 reg-staged (regs prefetched
// one tile ahead, cvt_pk + ds_write); AF32=0 bf16 via global_load_lds.
// 128x128 tile, BK=32, 4 waves as 2x2 of 64x64. 1D grid, bijective XCD swizzle.
// TRANSC=1: write C transposed per 1024-row panel (V^T layout for attention).
// ---------------------------------------------------------------------------
template <int RELU, int AF32, int TRANSC>
__global__ __launch_bounds__(256) void gemm_bt_kernel(
    const void* __restrict__ A, const u16* __restrict__ Bt,
    const float* __restrict__ bias, u16* __restrict__ C,
    int M, int N, int K) {
  __shared__ u16 As[2][128][32];
  __shared__ u16 Bs[2][128][32];
  const int tid = threadIdx.x;
  const int lane = tid & 63;
  const int wave = tid >> 6;
  const int wm = wave >> 1, wn = wave & 1;
  // bijective XCD swizzle
  const int nwg = gridDim.x;
  const int orig = blockIdx.x;
  const int q = nwg >> 3, r = nwg & 7;
  const int xcd = orig & 7, loc = orig >> 3;
  const int wgid = (xcd < r ? xcd * (q + 1) : r * (q + 1) + (xcd - r) * q) + loc;
  const int NT = N >> 7;
  const int tn = wgid % NT, tm = wgid / NT;
  const size_t abase = (size_t)tm * 128 * K;
  const size_t bbase = (size_t)tn * 128 * K;
  const int fr = lane & 15;            // frag row/col
  const int fk = (lane >> 4) << 3;     // frag k offset
  // global_load_lds staging coords: lane i covers row (i>>2), k-chunk (i&3)*8
  const int grow = lane >> 2;
  const int gkoff = (lane & 3) << 3;
  const u16* bgp = Bt + bbase + (size_t)(wave * 32 + grow) * K + gkoff;
  const u16* agp = (const u16*)A + abase + (size_t)(wave * 32 + grow) * K + gkoff;
  const int lr = tid >> 2;             // AF32 reg-staging: rows 0..63 (+64)
  const int lk = (tid & 3) << 3;
  const float* afp  = (const float*)A + abase + (size_t)lr * K + lk;
  const float* afp2 = afp + (size_t)64 * K;
  const int nk = K >> 5;
  f32x4 acc[4][4] = {};
  f32x4 p0, p1, p2, p3;   // AF32 one-tile-ahead register prefetch

  // ---- prologue: stage tile 0 into buf 0; (AF32) prefetch rA(1) ----
  if (AF32) {
    p0 = *(const f32x4*)afp;  p1 = *(const f32x4*)(afp + 4);
    p2 = *(const f32x4*)afp2; p3 = *(const f32x4*)(afp2 + 4);
    *(s16x8*)&As[0][lr][lk]      = cvt8(p0, p1);
    *(s16x8*)&As[0][lr + 64][lk] = cvt8(p2, p3);
    const int k1 = (nk > 1) ? 32 : 0;
    p0 = *(const f32x4*)(afp + k1);  p1 = *(const f32x4*)(afp + k1 + 4);
    p2 = *(const f32x4*)(afp2 + k1); p3 = *(const f32x4*)(afp2 + k1 + 4);
  } else {
    gl16(agp, &As[0][wave * 32][0]);
    gl16(agp + (size_t)16 * K, &As[0][wave * 32 + 16][0]);
  }
  gl16(bgp, &Bs[0][wave * 32][0]);
  gl16(bgp + (size_t)16 * K, &Bs[0][wave * 32 + 16][0]);

  int c = 0;
  for (int t = 0; t < nk; ++t) {
    const int nb = c ^ 1;
    if (t + 1 < nk) {
      if (AF32) {
        *(s16x8*)&As[nb][lr][lk]      = cvt8(p0, p1);   // rA(t+1) -> LDS
        *(s16x8*)&As[nb][lr + 64][lk] = cvt8(p2, p3);
        const int k2 = ((t + 2 < nk) ? (t + 2) : (nk - 1)) << 5;
        p0 = *(const f32x4*)(afp + k2);  p1 = *(const f32x4*)(afp + k2 + 4);
        p2 = *(const f32x4*)(afp2 + k2); p3 = *(const f32x4*)(afp2 + k2 + 4);
      } else {
        gl16(agp + (t + 1) * 32, &As[nb][wave * 32][0]);
        gl16(agp + (t + 1) * 32 + (size_t)16 * K, &As[nb][wave * 32 + 16][0]);
      }
      gl16(bgp + (t + 1) * 32, &Bs[nb][wave * 32][0]);
      gl16(bgp + (t + 1) * 32 + (size_t)16 * K, &Bs[nb][wave * 32 + 16][0]);
    }
    __builtin_amdgcn_sched_barrier(0);
    if (t + 1 < nk) {
      // AF32: {rA(t+2) 4 + B(t+1) 2} newest -> 6 ; gl16: {A,B}(t+1) -> 4
      asm volatile("s_waitcnt vmcnt(%0)" ::"n"(AF32 ? 6 : 4) : "memory");
    } else {
      asm volatile("s_waitcnt vmcnt(0)" ::: "memory");
    }
    if (AF32) asm volatile("s_waitcnt lgkmcnt(0)" ::: "memory");
    __builtin_amdgcn_sched_barrier(0);
    __builtin_amdgcn_s_barrier();        // buf[c] ready for all waves
    __builtin_amdgcn_sched_barrier(0);

    bf16x8 af[4], bfv[4];
#pragma unroll
    for (int i = 0; i < 4; ++i)
      af[i] = __builtin_bit_cast(bf16x8, *(const s16x8*)&As[c][wm * 64 + i * 16 + fr][fk]);
#pragma unroll
    for (int j = 0; j < 4; ++j)
      bfv[j] = __builtin_bit_cast(bf16x8, *(const s16x8*)&Bs[c][wn * 64 + j * 16 + fr][fk]);
#pragma unroll
    for (int i = 0; i < 4; ++i)
#pragma unroll
      for (int j = 0; j < 4; ++j)
        acc[i][j] = __builtin_amdgcn_mfma_f32_16x16x32_bf16(af[i], bfv[j], acc[i][j], 0, 0, 0);
    __builtin_amdgcn_s_barrier();        // all reads of buf[c] done
    c = nb;
  }

  // C/D layout: col = lane&15, row = (lane>>4)*4 + reg
  const int row0 = tm * 128 + wm * 64 + ((lane >> 4) << 2);
  const int col0 = tn * 128 + wn * 64 + fr;
  if (TRANSC) {
#pragma unroll
    for (int j = 0; j < 4; ++j) {
      const int col = col0 + j * 16;
      const float bv = bias[col];
#pragma unroll
      for (int i = 0; i < 4; ++i) {
        const int row = row0 + i * 16;   // rows row..row+3 contiguous, same panel
        u16x4 pk;
#pragma unroll
        for (int r2 = 0; r2 < 4; ++r2) {
          float v = acc[i][j][r2] + bv;
          if (RELU) v = fmaxf(v, 0.f);
          pk[r2] = f2b(v);
        }
        size_t idx = ((size_t)(row >> 10) * N + col) * 1024 + (row & 1023);
        *(u16x4*)&C[idx] = pk;
      }
    }
  } else {
#pragma unroll
    for (int j = 0; j < 4; ++j) {
      const int col = col0 + j * 16;
      const float bv = bias[col];
#pragma unroll
      for (int i = 0; i < 4; ++i) {
#pragma unroll
        for (int r2 = 0; r2 < 4; ++r2) {
          float v = acc[i][j][r2] + bv;
          if (RELU) v = fmaxf(v, 0.f);
          C[(size_t)(row0 + i * 16 + r2) * N + col] = f2b(v);
        }
      }
    }
  }
}

// ---------------------------------------------------------------------------
__device__ __forceinline__ void block_stats(float s, float s2, float* red, int tid,
                                            float& S, float& S2) {
#pragma unroll
  for (int o = 32; o > 0; o >>= 1) { s += __shfl_xor(s, o); s2 += __shfl_xor(s2, o); }
  if ((tid & 63) == 0) { red[tid >> 6] = s; red[4 + (tid >> 6)] = s2; }
  __syncthreads();
  S = red[0] + red[1] + red[2] + red[3];
  S2 = red[4] + red[5] + red[6] + red[7];
}

// t = LN(2*y) with ln1 params; batch-invariant (100 x 768), f32 in/out
__global__ __launch_bounds__(256) void t_kernel(const float* __restrict__ y,
                                                const float* __restrict__ g,
                                                const float* __restrict__ bb,
                                                float* __restrict__ t) {
  const int l = blockIdx.x, tid = threadIdx.x;
  __shared__ float red[8];
  float xv[3], s = 0.f, s2 = 0.f;
#pragma unroll
  for (int i = 0; i < 3; ++i) {
    int e = tid + i * 256;
    float v = 2.f * y[(size_t)l * 768 + e];
    xv[i] = v; s += v; s2 += v * v;
  }
  float S, S2;
  block_stats(s, s2, red, tid, S, S2);
  float mean = S * (1.f / 768.f);
  float var = S2 * (1.f / 768.f) - mean * mean;
  float inv = rsqrtf(var + 1e-5f);
#pragma unroll
  for (int i = 0; i < 3; ++i) {
    int e = tid + i * 256;
    t[(size_t)l * 768 + e] = (xv[i] - mean) * inv * g[e] + bb[e];
  }
}

// q = t @ Wq^T + bq  (100 x 768, K=768), all f32. block per l.
__global__ __launch_bounds__(256) void q_kernel(const float* __restrict__ t,
                                                const float* __restrict__ Wq,
                                                const float* __restrict__ bq,
                                                float* __restrict__ q) {
  const int l = blockIdx.x, tid = threadIdx.x;
  __shared__ __align__(16) float ts[768];
  for (int i = tid; i < 768; i += 256) ts[i] = t[(size_t)l * 768 + i];
  __syncthreads();
  for (int e = tid; e < 768; e += 256) {
    const float* wr = Wq + (size_t)e * 768;
    float acc = bq[e];
    for (int j = 0; j < 768; j += 4) {
      f32x4 wv = *(const f32x4*)&wr[j];
      f32x4 tv = *(const f32x4*)&ts[j];
      acc += wv[0] * tv[0] + wv[1] * tv[1] + wv[2] * tv[2] + wv[3] * tv[3];
    }
    q[(size_t)l * 768 + e] = acc;
  }
}

// c2[l][j] = sum_d y[l,d] * pool[l, 768+d, j] + dup_bias[l*10+j]   (100 x 10)
__global__ __launch_bounds__(256) void c2_kernel(const float* __restrict__ y,
                                                 const float* __restrict__ pool,
                                                 const float* __restrict__ dbias,
                                                 float* __restrict__ c2) {
  const int l = blockIdx.x, tid = threadIdx.x, lane = tid & 63, w = tid >> 6;
  for (int j = w; j < 10; j += 4) {
    float acc = 0.f;
    for (int d = lane; d < 768; d += 64)
      acc += y[(size_t)l * 768 + d] * pool[((size_t)l * 1536 + 768 + d) * 10 + j];
#pragma unroll
    for (int o = 32; o > 0; o >>= 1) acc += __shfl_xor(acc, o);
    if (lane == 0) c2[l * 10 + j] = acc + dbias[l * 10 + j];
  }
}

// ---------------------------------------------------------------------------
// MFMA fused cross-attention (see round-1 notes). grid=(32,8), 512 thr, 8 waves.
// ---------------------------------------------------------------------------
__global__ __launch_bounds__(512) void attn_kernel(
    const float* __restrict__ q,      // 100 x 768 f32
    const u16* __restrict__ kmat,     // (32*1024) x 768 bf16
    const u16* __restrict__ vt,       // (32*768) x 1024 bf16: vt[b*768+h*96+d][s]
    u16* __restrict__ ao,             // 3200 x 768 bf16
    float* __restrict__ ascore) {     // 3200 x 1024 f32 (d_out)
  const int b = blockIdx.x;
  const int l0 = blockIdx.y * 13;
  __shared__ float sc[13][1028];                 // 53456 B (stride 1028: 2-way free)
  __shared__ __align__(16) u16 qs[16][96];       // 3072 B
  __shared__ float rinv[16];
  const int tid = threadIdx.x;
  const int lane = tid & 63;
  const int w = tid >> 6;            // 0..7
  const int fr = lane & 15;
  const int hi = lane >> 4;          // 0..3
  const int fk = hi << 3;            // 0,8,16,24
  const int sfr = (fr < 13) ? fr : 12;  // clamped PV A-row (rows 13..15 unused)
  float areg[26];
#pragma unroll
  for (int j = 0; j < 26; ++j) areg[j] = 0.f;

  for (int h = 0; h < 8; ++h) {
    // ---- stage q tile (bf16), rows >=13 or l>=100 zeroed ----
    for (int i = tid; i < 192; i += 512) {   // 16 rows x 12 chunks of 8
      int r = i / 12, c8 = (i % 12) * 8;
      int l = l0 + r;
      s16x8 v = {};
      if (r < 13 && l < 100) v = load8<1>(q, (size_t)l * 768 + h * 96 + c8);
      *(s16x8*)&qs[r][c8] = v;
    }
    __syncthreads();
    // ---- QK^T: wave w owns s in [w*128, w*128+128) ----
    bf16x8 af[3];
#pragma unroll
    for (int kk = 0; kk < 3; ++kk)
      af[kk] = __builtin_bit_cast(bf16x8, *(const s16x8*)&qs[fr][kk * 32 + fk]);
    const u16* kbase = kmat + (size_t)(b * 1024 + w * 128 + fr) * 768 + h * 96 + fk;
#pragma unroll 2
    for (int nt = 0; nt < 8; ++nt) {
      f32x4 acc = {};
      const u16* kp = kbase + (size_t)nt * 16 * 768;
#pragma unroll
      for (int kk = 0; kk < 3; ++kk) {
        bf16x8 bf = __builtin_bit_cast(bf16x8, *(const s16x8*)(kp + kk * 32));
        acc = __builtin_amdgcn_mfma_f32_16x16x32_bf16(af[kk], bf, acc, 0, 0, 0);
      }
      const int s = w * 128 + nt * 16 + fr;
#pragma unroll
      for (int r = 0; r < 4; ++r) {
        int lr2 = hi * 4 + r;
        if (lr2 < 13) sc[lr2][s] = acc[r] * 0.10206207261596575f;  // 1/sqrt(96)
      }
    }
    __syncthreads();
    // ---- softmax: wave w rows {w, w+8}; store UNNORMALIZED exp + rinv ----
    for (int r = w; r < 13; r += 8) {
      float m = -1e30f;
      for (int i = lane; i < 1024; i += 64) m = fmaxf(m, sc[r][i]);
#pragma unroll
      for (int o = 32; o > 0; o >>= 1) m = fmaxf(m, __shfl_xor(m, o));
      float sum = 0.f;
      for (int i = lane; i < 1024; i += 64) {
        float e = __expf(sc[r][i] - m);
        sc[r][i] = e; sum += e;
      }
#pragma unroll
      for (int o = 32; o > 0; o >>= 1) sum += __shfl_xor(sum, o);
      if (lane == 0) rinv[r] = 1.f / sum;
    }
    __syncthreads();
    // ---- a_score: accumulate normalized probs in registers ----
#pragma unroll
    for (int j = 0; j < 26; ++j) {
      int i = tid + j * 512;
      int r = i >> 10;
      areg[j] += sc[r][i & 1023] * rinv[r];
    }
    // ---- PV: wave w owns k (=s) in [w*128, w*128+128), 4 k-steps ----
    f32x4 pacc[6];
#pragma unroll
    for (int nt = 0; nt < 6; ++nt) pacc[nt] = (f32x4){0.f, 0.f, 0.f, 0.f};
    const u16* vbase = vt + (size_t)(b * 768 + h * 96 + fr) * 1024 + w * 128 + fk;
#pragma unroll 2
    for (int ks = 0; ks < 4; ++ks) {
      const float* sp = &sc[sfr][w * 128 + ks * 32 + fk];
      bf16x8 paf;
#pragma unroll
      for (int j2 = 0; j2 < 8; ++j2) paf[j2] = (__bf16)sp[j2];
#pragma unroll
      for (int nt = 0; nt < 6; ++nt) {
        bf16x8 vf = __builtin_bit_cast(bf16x8,
            *(const s16x8*)(vbase + (size_t)nt * 16 * 1024 + ks * 32));
        pacc[nt] = __builtin_amdgcn_mfma_f32_16x16x32_bf16(paf, vf, pacc[nt], 0, 0, 0);
      }
    }
    __syncthreads();   // all sc reads done; reuse sc as partial buffer
    float* red = &sc[0][0];
#pragma unroll
    for (int nt = 0; nt < 6; ++nt) {
#pragma unroll
      for (int r = 0; r < 4; ++r) {
        int lr2 = hi * 4 + r;
        if (lr2 < 13) red[(w * 13 + lr2) * 96 + nt * 16 + fr] = pacc[nt][r];
      }
    }
    __syncthreads();
    // ---- cross-wave reduce + ao write (apply rinv here: flash-style) ----
    for (int i = tid; i < 1248; i += 512) {
      int lr2 = i / 96, d = i % 96;
      float s = 0.f;
#pragma unroll
      for (int w8 = 0; w8 < 8; ++w8) s += red[(w8 * 13 + lr2) * 96 + d];
      int l = l0 + lr2;
      if (l < 100) ao[(size_t)(b * 100 + l) * 768 + h * 96 + d] = f2b(s * rinv[lr2]);
    }
    __syncthreads();
  }
  // ---- write a_score mean ----
#pragma unroll
  for (int j = 0; j < 26; ++j) {
    int i = tid + j * 512;
    int r = i >> 10;
    int l = l0 + r;
    if (l < 100) ascore[(size_t)(b * 100 + l) * 1024 + (i & 1023)] = areg[j] * 0.125f;
  }
}

// ---------------------------------------------------------------------------
// out = LN(base + add) ; base f32 (per-l if flag, else per-row), add bf16.
// ---------------------------------------------------------------------------
__global__ __launch_bounds__(256) void ln_kernel(
    const float* __restrict__ base, const u16* __restrict__ add,
    const float* __restrict__ g, const float* __restrict__ bb,
    float* __restrict__ outf, u16* __restrict__ outb, int base_per_l) {
  const int row = blockIdx.x, tid = threadIdx.x;
  __shared__ float red[8];
  const size_t boff = (size_t)(base_per_l ? (row % 100) : row) * 768;
  const size_t aoff = (size_t)row * 768;
  float xv[3], s = 0.f, s2 = 0.f;
#pragma unroll
  for (int i = 0; i < 3; ++i) {
    int e = tid + i * 256;
    float v = base[boff + e] + b2f(add[aoff + e]);
    xv[i] = v; s += v; s2 += v * v;
  }
  float S, S2;
  block_stats(s, s2, red, tid, S, S2);
  float mean = S * (1.f / 768.f);
  float var = S2 * (1.f / 768.f) - mean * mean;
  float inv = rsqrtf(var + 1e-5f);
#pragma unroll
  for (int i = 0; i < 3; ++i) {
    int e = tid + i * 256;
    float o = (xv[i] - mean) * inv * g[e] + bb[e];
    if (outf) outf[aoff + e] = o;
    if (outb) outb[aoff + e] = f2b(o);
  }
}

// ---------------------------------------------------------------------------
// logits[b, l*10+j] = sum_{d<768} h[b,l,d] * pool[l,d,j] + c2[l,j]. block per l.
// ---------------------------------------------------------------------------
__global__ __launch_bounds__(256) void groupfc_kernel(
    const u16* __restrict__ h, const float* __restrict__ pool,
    const float* __restrict__ c2, float* __restrict__ logits) {
  const int l = blockIdx.x, tid = threadIdx.x;
  __shared__ float ps[768][10];
  for (int i = tid; i < 7680; i += 256) ps[i / 10][i % 10] = pool[(size_t)l * 15360 + i];
  __syncthreads();
  for (int idx = tid; idx < 320; idx += 256) {
    int bb = idx / 10, j = idx % 10;
    const u16* hr = h + (size_t)(bb * 100 + l) * 768;
    float acc = c2[l * 10 + j];
    for (int d0 = 0; d0 < 768; d0 += 8) {
      s16x8 hv = *(const s16x8*)&hr[d0];
#pragma unroll
      for (int e = 0; e < 8; ++e) acc += b2f((u16)hv[e]) * ps[d0 + e][j];
    }
    logits[bb * 1000 + l * 10 + j] = acc;
  }
}

// ---------------------------------------------------------------------------
extern "C" void kernel_launch(void* const* d_in, const int* in_sizes, int n_in,
                              void* d_out, int out_size, void* d_ws, size_t ws_size,
                              hipStream_t stream) {
  (void)in_sizes; (void)n_in; (void)out_size; (void)ws_size;
  const float* x      = (const float*)d_in[0];
  const float* y      = (const float*)d_in[1];
  const float* embedW = (const float*)d_in[2];
  const float* embedb = (const float*)d_in[3];
  const float* Wq     = (const float*)d_in[4];
  const float* Wk     = (const float*)d_in[5];
  const float* Wv     = (const float*)d_in[6];
  const float* bq     = (const float*)d_in[7];
  const float* bk     = (const float*)d_in[8];
  const float* bv     = (const float*)d_in[9];
  const float* Wo     = (const float*)d_in[10];
  const float* bo     = (const float*)d_in[11];
  const float* ln1g   = (const float*)d_in[12];
  const float* ln1b   = (const float*)d_in[13];
  const float* ln2g   = (const float*)d_in[14];
  const float* ln2b   = (const float*)d_in[15];
  const float* ln3g   = (const float*)d_in[16];
  const float* ln3b   = (const float*)d_in[17];
  const float* W1     = (const float*)d_in[18];
  const float* b1     = (const float*)d_in[19];
  const float* W2     = (const float*)d_in[20];
  const float* b2     = (const float*)d_in[21];
  const float* pool   = (const float*)d_in[22];
  const float* dbias  = (const float*)d_in[23];

  // Workspace layout (peak ~153.2 MB): kws | vt | R(mem, then post-attn) | small
  char* w = (char*)d_ws;
  u16* kws = (u16*)(w);                         // 50,331,648 B
  u16* vt  = (u16*)(w + 50331648);              // 50,331,648 B (V^T panels)
  char* R  = w + 100663296;                     // 50,331,648 B region
  u16*   mem = (u16*)R;                         // dead after V-projection
  u16*   ao  = (u16*)(R + 0);
  u16*   u1  = (u16*)(R + 4915200);
  u16*   t2b = (u16*)(R + 9830400);
  u16*   f1  = (u16*)(R + 14745600);
  u16*   f2  = (u16*)(R + 19660800);
  u16*   hb  = (u16*)(R + 24576000);
  float* t2f = (float*)(R + 29491200);          // +9,830,400 B ends at 39,321,600
  float* tf  = (float*)(w + 150994944);
  float* qf  = (float*)(w + 150994944 + 307200);
  float* c2  = (float*)(w + 150994944 + 614400);
  // bf16 weight staging (liveness-overlapped):
  u16* wbE = (u16*)(w + 50331648);              // in vt (dead before V-proj writes)
  u16* wbK = (u16*)(w + 50331648 + 3145728);    // in vt, read by K-proj only
  u16* wbV = (u16*)(w + 150994944 + 1048576);   // own slot (+1.18 MB, peak 153.2 MB)
  u16* wbO = (u16*)(w + 0);                     // in kws (dead after attn)
  u16* wb1 = (u16*)(w + 1179648);
  u16* wb2 = (u16*)(w + 2359296);

  float* logits = (float*)d_out;
  float* ascore = (float*)d_out + 32000;

  cvt_kernel<<<dim3(768), dim3(256), 0, stream>>>(embedW, wbE, 196608);
  cvt_kernel<<<dim3(288), dim3(256), 0, stream>>>(Wk, wbK, 73728);
  cvt_kernel<<<dim3(288), dim3(256), 0, stream>>>(Wv, wbV, 73728);
  t_kernel<<<dim3(100), dim3(256), 0, stream>>>(y, ln1g, ln1b, tf);
  q_kernel<<<dim3(100), dim3(256), 0, stream>>>(tf, Wq, bq, qf);
  c2_kernel<<<dim3(100), dim3(256), 0, stream>>>(y, pool, dbias, c2);

  gemm_bt_kernel<1, 1, 0><<<dim3(1536), dim3(256), 0, stream>>>(x, wbE, embedb, mem, 32768, 768, 2048);
  gemm_bt_kernel<0, 0, 0><<<dim3(1536), dim3(256), 0, stream>>>(mem, wbK, bk, kws, 32768, 768, 768);
  gemm_bt_kernel<0, 0, 1><<<dim3(1536), dim3(256), 0, stream>>>(mem, wbV, bv, vt, 32768, 768, 768);

  attn_kernel<<<dim3(32, 8), dim3(512), 0, stream>>>(qf, kws, vt, ao, ascore);

  cvt3_kernel<<<dim3(288, 3), dim3(256), 0, stream>>>(Wo, W1, W2, wbO, wb1, wb2, 73728);
  gemm_bt_kernel<0, 0, 0><<<dim3(150), dim3(256), 0, stream>>>(ao, wbO, bo, u1, 3200, 768, 768);
  ln_kernel<<<dim3(3200), dim3(256), 0, stream>>>(tf, u1, ln2g, ln2b, t2f, t2b, 1);
  gemm_bt_kernel<1, 0, 0><<<dim3(150), dim3(256), 0, stream>>>(t2b, wb1, b1, f1, 3200, 768, 768);
  gemm_bt_kernel<0, 0, 0><<<dim3(150), dim3(256), 0, stream>>>(f1, wb2, b2, f2, 3200, 768, 768);
  ln_kernel<<<dim3(3200), dim3(256), 0, stream>>>(t2f, f2, ln3g, ln3b, (float*)nullptr, hb, 0);
  groupfc_kernel<<<dim3(100), dim3(256), 0, stream>>>(hb, pool, c2, logits);
}